// Round 1
// baseline (398.596 us; speedup 1.0000x reference)
//
#include <hip/hip_runtime.h>
#include <math.h>

#define EPS 1e-7f
#define RPB 256   // rows per block == threads per block

__global__ __launch_bounds__(256) void loc_loss_kernel(
    const float* __restrict__ pred,   // (B, 30)
    const float* __restrict__ tgt,    // (B, 5)
    float* __restrict__ out,          // scalar
    float inv_b)
{
    __shared__ float s_pred[RPB * 30];   // 30720 B
    __shared__ float s_tgt [RPB * 5];    //  5120 B
    __shared__ float s_red [4];

    const int t = threadIdx.x;
    const size_t blk = blockIdx.x;

    // ---- coalesced global -> LDS staging (float4) ----
    const float4* gp = (const float4*)(pred + blk * (size_t)(RPB * 30));
    const float4* gt = (const float4*)(tgt  + blk * (size_t)(RPB * 5));
    float4* sp = (float4*)s_pred;
    float4* st = (float4*)s_tgt;
    #pragma unroll
    for (int k = t; k < (RPB * 30) / 4; k += 256) sp[k] = gp[k];
    for (int k = t; k < (RPB * 5) / 4;  k += 256) st[k] = gt[k];
    __syncthreads();

    // ---- per-thread row compute ----
    const float* pr = s_pred + t * 30;
    const float* tb = s_tgt  + t * 5;

    const int   label = (int)tb[0];
    const float x2 = tb[1], y2 = tb[2], w2 = tb[3], h2 = tb[4];
    const float at2  = atanf(w2 / (h2 + EPS));
    const float area2 = w2 * h2;
    const float hw2 = 0.5f * w2, hh2 = 0.5f * h2;
    const float b2x1 = x2 - hw2, b2x2 = x2 + hw2;
    const float b2y1 = y2 - hh2, b2y2 = y2 + hh2;
    const float C_PI2 = 4.0f / (float)(M_PI * M_PI);

    float acc = 0.0f;

    #pragma unroll
    for (int a = 0; a < 3; ++a) {
        const float* q = pr + a * 10;

        // log-softmax over 5 classes, pick label
        float c0 = q[0], c1 = q[1], c2c = q[2], c3 = q[3], c4 = q[4];
        float m = fmaxf(fmaxf(fmaxf(c0, c1), fmaxf(c2c, c3)), c4);
        float s = __expf(c0 - m) + __expf(c1 - m) + __expf(c2c - m)
                + __expf(c3 - m) + __expf(c4 - m);
        float lse = m + __logf(s);
        float picked = q[label] - lse;
        acc += (lse - q[label]) * inv_b;   // -picked / B
        (void)picked;

        const float conf = q[5];
        const float x1 = q[6], y1 = q[7], w1 = q[8], h1 = q[9];

        // l_bbox term
        float dx = x1 - x2, dy = y1 - y2, dw = w1 - w2, dh = h1 - h2;
        acc += dx * dx + dy * dy + dw * dw + dh * dh;

        // CIoU (stop-gradient: just a value here)
        float hw1 = 0.5f * w1, hh1 = 0.5f * h1;
        float b1x1 = x1 - hw1, b1x2 = x1 + hw1;
        float b1y1 = y1 - hh1, b1y2 = y1 + hh1;

        float iw = fminf(b1x2, b2x2) - fmaxf(b1x1, b2x1);
        float ih = fminf(b1y2, b2y2) - fmaxf(b1y1, b2y1);
        iw = fmaxf(iw, 0.0f); ih = fmaxf(ih, 0.0f);
        float inter = iw * ih;
        float uni   = w1 * h1 + area2 - inter + EPS;
        float iou   = inter / uni;

        float cw = fmaxf(b1x2, b2x2) - fminf(b1x1, b2x1);
        float ch = fmaxf(b1y2, b2y2) - fminf(b1y1, b2y1);
        float c2 = cw * cw + ch * ch + EPS;
        float rho2 = dx * dx + dy * dy;   // ((2x2-2x1)^2 + (2y2-2y1)^2)/4

        float at1 = atanf(w1 / (h1 + EPS));
        float dat = at2 - at1;
        float v = C_PI2 * dat * dat;
        float alpha = v / (v - iou + (1.0f + EPS));
        float ciou = iou - (rho2 / c2 + v * alpha);

        float dc = ciou - conf;
        acc += dc * dc;
    }

    // ---- reduction: wave shuffle -> LDS -> one atomic per block ----
    #pragma unroll
    for (int off = 32; off > 0; off >>= 1)
        acc += __shfl_down(acc, off, 64);

    const int wave = t >> 6;
    const int lane = t & 63;
    if (lane == 0) s_red[wave] = acc;
    __syncthreads();
    if (t == 0) {
        float bsum = s_red[0] + s_red[1] + s_red[2] + s_red[3];
        atomicAdd(out, bsum);
    }
}

extern "C" void kernel_launch(void* const* d_in, const int* in_sizes, int n_in,
                              void* d_out, int out_size, void* d_ws, size_t ws_size,
                              hipStream_t stream) {
    const float* pred = (const float*)d_in[0];
    const float* tgt  = (const float*)d_in[1];
    float* out = (float*)d_out;

    const int rows = in_sizes[0] / 30;       // 2097152
    const int grid = rows / RPB;             // 8192 (exact)
    const float inv_b = 1.0f / (float)rows;

    hipMemsetAsync(d_out, 0, (size_t)out_size * sizeof(float), stream);
    loc_loss_kernel<<<grid, RPB, 0, stream>>>(pred, tgt, out, inv_b);
}

// Round 3
// 360.958 us; speedup vs baseline: 1.1043x; 1.1043x over previous
//
#include <hip/hip_runtime.h>
#include <math.h>

#define EPS 1e-7f
#define RPB 256   // rows per block == threads per block

// fast atan, all signs/magnitudes, |err| < ~3e-7 rad: reduce to [0,1], odd minimax poly
__device__ __forceinline__ float fast_atan(float x) {
    float a = fabsf(x);
    float big = (a > 1.0f) ? 1.0f : 0.0f;
    float z = (a > 1.0f) ? __frcp_rn(a) : a;
    float z2 = z * z;
    float p = -0.0117212f;
    p = fmaf(p, z2,  0.05265332f);
    p = fmaf(p, z2, -0.11643287f);
    p = fmaf(p, z2,  0.19354346f);
    p = fmaf(p, z2, -0.33262347f);
    p = fmaf(p, z2,  0.99997726f);
    p = p * z;
    float r = big * (1.57079632679f - p) + (1.0f - big) * p;
    return copysignf(r, x);
}

__global__ __launch_bounds__(256) void loc_loss_kernel(
    const float* __restrict__ pred,   // (B, 30)
    const float* __restrict__ tgt,    // (B, 5)
    float* __restrict__ partial,      // (gridDim.x)
    float inv_b)
{
    __shared__ float s_pred[RPB * 30];   // 30720 B
    __shared__ float s_tgt [RPB * 5];    //  5120 B
    __shared__ float s_red [4];

    const int t = threadIdx.x;
    const size_t blk = blockIdx.x;

    // ---- coalesced global -> LDS staging (float4) ----
    const float4* gp = (const float4*)(pred + blk * (size_t)(RPB * 30));
    const float4* gt = (const float4*)(tgt  + blk * (size_t)(RPB * 5));
    float4* sp = (float4*)s_pred;
    float4* st = (float4*)s_tgt;
    #pragma unroll
    for (int k = t; k < (RPB * 30) / 4; k += 256) sp[k] = gp[k];
    for (int k = t; k < (RPB * 5) / 4;  k += 256) st[k] = gt[k];
    __syncthreads();

    // ---- per-thread row compute ----
    const float* pr = s_pred + t * 30;
    const float* tb = s_tgt  + t * 5;

    const int   label = (int)tb[0];
    const float x2 = tb[1], y2 = tb[2], w2 = tb[3], h2 = tb[4];
    const float at2   = fast_atan(__fdividef(w2, h2 + EPS));  // hoisted: target atan
    const float area2 = w2 * h2;
    const float hw2 = 0.5f * w2, hh2 = 0.5f * h2;
    const float b2x1 = x2 - hw2, b2x2 = x2 + hw2;
    const float b2y1 = y2 - hh2, b2y2 = y2 + hh2;
    const float C_PI2 = 4.0f / (float)(M_PI * M_PI);

    float acc = 0.0f;

    #pragma unroll
    for (int a = 0; a < 3; ++a) {
        const float* q = pr + a * 10;

        // log-softmax over 5 classes, pick label
        float c0 = q[0], c1 = q[1], c2c = q[2], c3 = q[3], c4 = q[4];
        float m = fmaxf(fmaxf(fmaxf(c0, c1), fmaxf(c2c, c3)), c4);
        float s = __expf(c0 - m) + __expf(c1 - m) + __expf(c2c - m)
                + __expf(c3 - m) + __expf(c4 - m);
        float lse = m + __logf(s);
        acc += (lse - q[label]) * inv_b;   // -picked / B

        const float conf = q[5];
        const float x1 = q[6], y1 = q[7], w1 = q[8], h1 = q[9];

        // l_bbox term
        float dx = x1 - x2, dy = y1 - y2, dw = w1 - w2, dh = h1 - h2;
        acc += dx * dx + dy * dy + dw * dw + dh * dh;

        // CIoU (stop-gradient: just a value here)
        float hw1 = 0.5f * w1, hh1 = 0.5f * h1;
        float b1x1 = x1 - hw1, b1x2 = x1 + hw1;
        float b1y1 = y1 - hh1, b1y2 = y1 + hh1;

        float iw = fminf(b1x2, b2x2) - fmaxf(b1x1, b2x1);
        float ih = fminf(b1y2, b2y2) - fmaxf(b1y1, b2y1);
        iw = fmaxf(iw, 0.0f); ih = fmaxf(ih, 0.0f);
        float inter = iw * ih;
        float uni   = w1 * h1 + area2 - inter + EPS;
        float iou   = __fdividef(inter, uni);

        float cw = fmaxf(b1x2, b2x2) - fminf(b1x1, b2x1);
        float ch = fmaxf(b1y2, b2y2) - fminf(b1y1, b2y1);
        float c2 = cw * cw + ch * ch + EPS;
        float rho2 = dx * dx + dy * dy;   // ((2x2-2x1)^2+(2y2-2y1)^2)/4

        // NOTE: atan-difference identity is INVALID here (r1 can be negative,
        // 1+r1*r2 can cross 0 -> ±pi branch error, cost 3.7e6 absmax in R2).
        // Keep separate atans.
        float at1 = fast_atan(__fdividef(w1, h1 + EPS));
        float dat = at2 - at1;
        float v = C_PI2 * dat * dat;
        float alpha = __fdividef(v, v - iou + (1.0f + EPS));
        float ciou = iou - (__fdividef(rho2, c2) + v * alpha);

        float dc = ciou - conf;
        acc += dc * dc;
    }

    // ---- reduction: wave shuffle -> LDS -> one partial per block ----
    #pragma unroll
    for (int off = 32; off > 0; off >>= 1)
        acc += __shfl_down(acc, off, 64);

    const int wave = t >> 6;
    const int lane = t & 63;
    if (lane == 0) s_red[wave] = acc;
    __syncthreads();
    if (t == 0)
        partial[blk] = s_red[0] + s_red[1] + s_red[2] + s_red[3];
}

__global__ __launch_bounds__(256) void reduce_kernel(
    const float* __restrict__ partial, float* __restrict__ out, int n4)
{
    __shared__ float s_red[4];
    float acc = 0.0f;
    for (int k = threadIdx.x; k < n4; k += 256) {
        float4 v = ((const float4*)partial)[k];
        acc += (v.x + v.y) + (v.z + v.w);
    }
    #pragma unroll
    for (int off = 32; off > 0; off >>= 1)
        acc += __shfl_down(acc, off, 64);
    if ((threadIdx.x & 63) == 0) s_red[threadIdx.x >> 6] = acc;
    __syncthreads();
    if (threadIdx.x == 0)
        out[0] = (s_red[0] + s_red[1]) + (s_red[2] + s_red[3]);
}

extern "C" void kernel_launch(void* const* d_in, const int* in_sizes, int n_in,
                              void* d_out, int out_size, void* d_ws, size_t ws_size,
                              hipStream_t stream) {
    const float* pred = (const float*)d_in[0];
    const float* tgt  = (const float*)d_in[1];
    float* out = (float*)d_out;
    float* partial = (float*)d_ws;           // 8192 floats = 32 KB scratch

    const int rows = in_sizes[0] / 30;       // 2097152
    const int grid = rows / RPB;             // 8192 (exact)
    const float inv_b = 1.0f / (float)rows;

    loc_loss_kernel<<<grid, RPB, 0, stream>>>(pred, tgt, partial, inv_b);
    reduce_kernel<<<1, 256, 0, stream>>>(partial, out, grid / 4);
}